// Round 13
// baseline (159.990 us; speedup 1.0000x reference)
//
#include <hip/hip_runtime.h>
#include <hip/hip_fp16.h>

typedef float    f32x4 __attribute__((ext_vector_type(4)));
typedef _Float16 f16x2 __attribute__((ext_vector_type(2)));
typedef _Float16 f16x4 __attribute__((ext_vector_type(4)));
typedef _Float16 f16x8 __attribute__((ext_vector_type(8)));

#define BS 8
#define NN 2048
#define DK 128
#define DM 64
#define MIXOFF (1024 * DK)  // halfs between mix-0 and mix-1 rows of one batch
// log2(e) / sqrt(128): folds softmax temperature AND exp->exp2 conversion into Q
#define QSCALE 0.12751744116926208f

#define MFMA32(a, b, c) __builtin_amdgcn_mfma_f32_16x16x32_f16((a), (b), (c), 0, 0, 0)
#define EXP2(x) __builtin_amdgcn_exp2f(x)

__device__ __forceinline__ f16x2 pkrtz(float x, float y) {
  return __builtin_bit_cast(f16x2, __builtin_amdgcn_cvt_pkrtz(x, y));
}

// async global->LDS DMA, 16B per lane; no VGPR transit (allocator-proof)
__device__ __forceinline__ void load_lds16(const _Float16* g, _Float16* l) {
  __builtin_amdgcn_global_load_lds(
      (const __attribute__((address_space(1))) void*)(uintptr_t)g,
      (__attribute__((address_space(3))) void*)(uint32_t)(uintptr_t)l, 16, 0, 0);
}

// global 16B load pinned to VGPRs via "=v" (R10's array buffers went AGPR-side
// and serialized through copies; asm constraint makes that impossible). No
// compiler waitcnt is emitted for asm loads — consumption happens after the
// next __syncthreads, whose vmcnt(0) drain (required for K staging) covers it.
__device__ __forceinline__ f16x8 gload16v(const _Float16* p) {
  f16x8 r;
  asm volatile("global_load_dwordx4 %0, %1, off" : "=v"(r) : "v"(p));
  return r;
}

// ---- fused prep: K f32->f16 (512 blk), V transpose 64x64 (512 blk), q-mean (64 blk) ----
__global__ void prep_k(const float* __restrict__ kt, _Float16* __restrict__ kh,
                       const float* __restrict__ vt, _Float16* __restrict__ vT,
                       const float* __restrict__ qt, float* __restrict__ qpart) {
  __shared__ float tile[64][65];
  __shared__ float red[256];
  int blk = blockIdx.x;
  int t = threadIdx.x;
  if (blk < 512) {
    size_t base = (size_t)blk * 4096;
#pragma unroll
    for (int j = 0; j < 4; ++j) {
      size_t i = base + j * 1024 + t * 4;
      f32x4 v = *(const f32x4*)(kt + i);
      f16x4 h;
      h[0] = (_Float16)v[0]; h[1] = (_Float16)v[1];
      h[2] = (_Float16)v[2]; h[3] = (_Float16)v[3];
      *(f16x4*)(kh + i) = h;
    }
  } else if (blk < 1024) {
    int i2 = blk - 512;
    int b = i2 >> 6;
    int rem = i2 & 63;
    int j0 = (rem & 31) * 64;   // key tile
    int c0 = (rem >> 5) * 64;   // channel tile
    int tx = t & 63, ty = t >> 6;
    const float* src = vt + ((size_t)b * NN + j0) * DK + c0;
#pragma unroll
    for (int rr = 0; rr < 16; ++rr) {
      int row = ty * 16 + rr;
      tile[row][tx] = src[(size_t)row * DK + tx];
    }
    __syncthreads();
    _Float16* dst = vT + ((size_t)b * DK + c0) * NN + j0;
    int chl = t >> 4;
    int k4 = (t & 15) * 4;
#pragma unroll
    for (int r2 = 0; r2 < 4; ++r2) {
      int ch = r2 * 16 + chl;
      f16x4 h;
      h[0] = (_Float16)tile[k4 + 0][ch]; h[1] = (_Float16)tile[k4 + 1][ch];
      h[2] = (_Float16)tile[k4 + 2][ch]; h[3] = (_Float16)tile[k4 + 3][ch];
      *(f16x4*)(dst + (size_t)ch * NN + k4) = h;
    }
  } else {
    int i = blk - 1024;
    int b = i >> 3, seg = i & 7;
    int c = t & 127, h = t >> 7;
    const float* p = qt + ((size_t)b * NN + seg * 256 + h * 128) * DK + c;
    float s = 0.f;
#pragma unroll 8
    for (int n = 0; n < 128; ++n) s += p[(size_t)n * DK];
    red[t] = s;
    __syncthreads();
    if (t < 128) qpart[(size_t)i * 128 + t] = red[t] + red[t + 128];
  }
}

// Stage step S: K ONLY, both key halves (2 x 8KB). 1024 16B units, 512 thr x 2.
// V is NOT staged (direct global->VGPR). Unit map/swizzle verified R6/R8/R12.
#define STAGE(BUF, S) do {                                                \
    _Float16* db_ = stg + (BUF) * 8192;                                   \
    load_lds16(khg + gKst + (S) * 2048, db_ + t * 8);                     \
    load_lds16(khg + gKst + 65536 + (S) * 2048, db_ + 4096 + t * 8);      \
  } while (0)

// V register prefetch for step S (8KB tile of this wave's kh half), asm-pinned
// VGPRs, constant indices. Completes at the next barrier's vmcnt(0) drain.
#define VLOAD(VF, S) do {                                                 \
    _Pragma("unroll")                                                     \
    for (int cc = 0; cc < 8; ++cc)                                        \
      VF[cc] = gload16v(vp0 + (size_t)(cc * 16) * NN + (S) * 32);         \
  } while (0)

// One 32-key step: K frags from LDS buffer BUF (this wave's kh/mix), V from VF.
#define CSTEP(BUF, VF) do {                                               \
    const _Float16* sb_ = stg + (BUF) * 8192 + khoff;                     \
    f16x8 kf0 = *(const f16x8*)(sb_ + kr0 + kA);                          \
    f16x8 kf1 = *(const f16x8*)(sb_ + kr0 + kB);                          \
    f16x8 kf2 = *(const f16x8*)(sb_ + kr1 + kA);                          \
    f16x8 kf3 = *(const f16x8*)(sb_ + kr1 + kB);                          \
    _Pragma("unroll")                                                     \
    for (int su = 0; su < 2; ++su) {                                      \
      f32x4 s0 = MFMA32(kf1, qf[su][1], MFMA32(kf0, qf[su][0], z));       \
      f32x4 s1 = MFMA32(kf3, qf[su][1], MFMA32(kf2, qf[su][0], z));       \
      float e0 = EXP2(s0[0]), e1 = EXP2(s0[1]), e2 = EXP2(s0[2]), e3 = EXP2(s0[3]); \
      float e4 = EXP2(s1[0]), e5 = EXP2(s1[1]), e6 = EXP2(s1[2]), e7 = EXP2(s1[3]); \
      lsum[su] += ((e0 + e1) + (e2 + e3)) + ((e4 + e5) + (e6 + e7));      \
      union { f16x8 v; f16x2 h[4]; } w;                                   \
      w.h[0] = pkrtz(e0, e1); w.h[1] = pkrtz(e2, e3);                     \
      w.h[2] = pkrtz(e4, e5); w.h[3] = pkrtz(e6, e7);                     \
      _Pragma("unroll")                                                   \
      for (int cc = 0; cc < 8; ++cc)                                      \
        acc[su][cc] = MFMA32(VF[cc], w.v, acc[su][cc]);                   \
    }                                                                     \
  } while (0)

// ---------------- main: mixture flash attention -------------------------------
// grid 256 x 512thr (1 blk/CU): b=blk&7, qb=blk>>3 (64 q/block).
// Wave = (m, kh, u): mix, key-half (in-block split-K), 32-q tile. R12 structure
// but V bypasses LDS: staged bytes/step 32KB -> 16KB (K only). R8/R12 showed the
// step is bound by the staging-drain chain, not LDS reads — halving staged bytes
// attacks the binder. V: 8KB/step L1-resident (8 waves share), asm-VGPR dbuf.
// kh merge via LDS epilogue phases; prior softmax redundant per block.
__global__ __launch_bounds__(512, 2) void attn_k(const float* __restrict__ qt,
                                                 const _Float16* __restrict__ khg,
                                                 const _Float16* __restrict__ vTg,
                                                 const float* __restrict__ kern,
                                                 const float* __restrict__ qpart,
                                                 float* __restrict__ out) {
  __shared__ __align__(16) char smem[40960];
  _Float16* stg = (_Float16*)smem;  // [2][8192] halfs = 2 x 16KB K staging
  const int b = blockIdx.x & 7;
  const int qb = blockIdx.x >> 3;
  const int t = threadIdx.x;
  const int wv = t >> 6;
  const int m = wv >> 2;        // mixture
  const int kh = (wv >> 1) & 1; // key half (in-block split-K)
  const int u = wv & 1;         // 32-query tile
  const int lane = t & 63;
  const int quad = lane >> 4, l16 = lane & 15;
  const int perm = ((l16 >> 2) << 3) | (l16 & 3);
  const int bq = b * (NN * DK);
  const int bV = b * (DK * NN);

  // Q fragments: 2 subtiles x 2 chunks, f32 load + scale + pack in-register
  f16x8 qf[2][2];  // [su][chunk]
#pragma unroll
  for (int su = 0; su < 2; ++su)
#pragma unroll
    for (int c = 0; c < 2; ++c) {
      const float* qp_ = qt + bq + m * MIXOFF +
                         (qb * 64 + u * 32 + su * 16 + l16) * DM + quad * 8 + c * 32;
      f32x4 v0 = *(const f32x4*)qp_;
      f32x4 v1 = *(const f32x4*)(qp_ + 4);
      union { f16x8 v; f16x2 h[4]; } w;
      w.h[0] = pkrtz(v0[0] * QSCALE, v0[1] * QSCALE);
      w.h[1] = pkrtz(v0[2] * QSCALE, v0[3] * QSCALE);
      w.h[2] = pkrtz(v1[0] * QSCALE, v1[1] * QSCALE);
      w.h[3] = pkrtz(v1[2] * QSCALE, v1[3] * QSCALE);
      qf[su][c] = w.v;
    }

  // staging offsets (halfs): thread t stages K unit t of each kh tile (R6 map)
  const int mixu = t >> 8;
  const int qq8 = t & 255;
  const int rK = qq8 >> 3;
  const int uuK = (qq8 & 7) ^ ((rK & 3) ^ ((rK >> 3) << 1));
  const int gKst = bq + mixu * MIXOFF + rK * 64 + uuK * 8;

  // LDS K read offsets (halfs) within this wave's kh tile (verified maps)
  const int gK = (l16 & 3) ^ ((l16 >> 2) << 1);
  const int kA = (quad ^ gK) * 8;
  const int kB = ((quad + 4) ^ gK) * 8;
  const int kr0 = m * 2048 + perm * 64;
  const int kr1 = m * 2048 + (perm + 4) * 64;
  const int khoff = kh * 4096;

  // V global base for this wave's key half (layout verified R9/R10: identical
  // absmax): lane holds V^T[ch=cc*16+l16][kh*1024 + s*32 + quad*8 ..+7]
  const _Float16* vp0 = vTg + bV + (size_t)l16 * NN + kh * 1024 + quad * 8;

  const f32x4 z = {0.f, 0.f, 0.f, 0.f};
  f32x4 acc[2][8];  // [su][cc]
  float lsum[2] = {0.f, 0.f};
#pragma unroll
  for (int su = 0; su < 2; ++su)
#pragma unroll
    for (int cc = 0; cc < 8; ++cc) acc[su][cc] = z;

  f16x8 va[8], vb[8];
  STAGE(0, 0);
  VLOAD(va, 0);
  for (int s = 0; s < 32; s += 2) {
    __syncthreads();  // K tile s + V(s) drained; reads of buf1 (s-1) done
    STAGE(1, s + 1);
    VLOAD(vb, s + 1);
    CSTEP(0, va);
    __syncthreads();  // K tile s+1 + V(s+1) drained; reads of buf0 done
    if (s + 2 < 32) STAGE(0, s + 2);
    VLOAD(va, (s + 2) & 31);  // wrap on last pair: harmless warm reload
    CSTEP(1, vb);
  }
  __syncthreads();  // all tile reads done; epilogue overlays staging LDS

  // ---- epilogue LDS overlay ----
  float* obuf = (float*)smem;                  // [64][132] floats (33792 B)
  float* barL = (float*)(smem + 33792);        // [8][128]
  float* lgp = (float*)(smem + 37888);
  float* exq = (float*)(smem + 37952);
  float* prp = (float*)(smem + 38016);
  float* lbuf = (float*)(smem + 38144);        // [2][64]: l merged over kh

  // l: reduce across quads, then merge kh halves via lbuf
#pragma unroll
  for (int su = 0; su < 2; ++su) {
    lsum[su] += __shfl_xor(lsum[su], 16);
    lsum[su] += __shfl_xor(lsum[su], 32);
  }
  // prior softmax inputs (redundant per block) — interleave with l merge
  for (int e = t; e < 1024; e += 512) {
    int bb = e >> 7, c = e & 127;
    float ss = 0.f;
#pragma unroll
    for (int seg = 0; seg < 8; ++seg) ss += qpart[(size_t)(bb * 8 + seg) * 128 + c];
    barL[e] = ss * (1.0f / 2048.0f);
  }
  if (kh == 0 && quad == 0)
#pragma unroll
    for (int su = 0; su < 2; ++su) lbuf[m * 64 + u * 32 + su * 16 + l16] = lsum[su];
  __syncthreads();
  if (kh == 1 && quad == 0)
#pragma unroll
    for (int su = 0; su < 2; ++su) lbuf[m * 64 + u * 32 + su * 16 + l16] += lsum[su];
  if (t < 16) {
    int mm = t >> 3, bb = t & 7;
    float ss = 0.f;
    for (int c = 0; c < DK; ++c) ss += kern[mm * DK + c] * barL[bb * 128 + c];
    lgp[t] = ss;
  }
  __syncthreads();
  if (t < 16) {
    int mm = t >> 3;
    float mx = lgp[mm * 8];
    for (int i = 1; i < 8; ++i) mx = fmaxf(mx, lgp[mm * 8 + i]);
    exq[t] = __expf(lgp[t] - mx);
  }
  __syncthreads();
  if (t < 16) {
    int mm = t >> 3;
    float sm = 0.f;
    for (int i = 0; i < 8; ++i) sm += exq[mm * 8 + i];
    prp[t] = exq[t] / sm;  // flat[m*8+b]; read as [b*2+m] (TF reshape quirk)
  }
  __syncthreads();

  const float wm = prp[b * 2 + m];
  float rr[2];
#pragma unroll
  for (int su = 0; su < 2; ++su)
    rr[su] = wm / lbuf[m * 64 + u * 32 + su * 16 + l16];

  // ---- 4-phase LDS merge: obuf = (m0kh0 + m0kh1)*r0 + m1kh0*r1 + m1kh1*r1 ----
  if (m == 0 && kh == 0) {
#pragma unroll
    for (int su = 0; su < 2; ++su) {
      int r_ = (u * 32 + su * 16 + l16) * 132 + quad * 4;
#pragma unroll
      for (int cc = 0; cc < 8; ++cc) *(f32x4*)&obuf[r_ + cc * 16] = acc[su][cc];
    }
  }
  __syncthreads();
  if (m == 0 && kh == 1) {  // add + scale by r0 (l already merged over kh)
#pragma unroll
    for (int su = 0; su < 2; ++su) {
      int r_ = (u * 32 + su * 16 + l16) * 132 + quad * 4;
#pragma unroll
      for (int cc = 0; cc < 8; ++cc) {
        f32x4 o = *(const f32x4*)&obuf[r_ + cc * 16];
#pragma unroll
        for (int e = 0; e < 4; ++e) o[e] = (o[e] + acc[su][cc][e]) * rr[su];
        *(f32x4*)&obuf[r_ + cc * 16] = o;
      }
    }
  }
  __syncthreads();
  if (m == 1 && kh == 0) {
#pragma unroll
    for (int su = 0; su < 2; ++su) {
      int r_ = (u * 32 + su * 16 + l16) * 132 + quad * 4;
#pragma unroll
      for (int cc = 0; cc < 8; ++cc) {
        f32x4 o = *(const f32x4*)&obuf[r_ + cc * 16];
#pragma unroll
        for (int e = 0; e < 4; ++e) o[e] += acc[su][cc][e] * rr[su];
        *(f32x4*)&obuf[r_ + cc * 16] = o;
      }
    }
  }
  __syncthreads();
  if (m == 1 && kh == 1) {
#pragma unroll
    for (int su = 0; su < 2; ++su) {
      int r_ = (u * 32 + su * 16 + l16) * 132 + quad * 4;
#pragma unroll
      for (int cc = 0; cc < 8; ++cc) {
        f32x4 o = *(const f32x4*)&obuf[r_ + cc * 16];
#pragma unroll
        for (int e = 0; e < 4; ++e) o[e] += acc[su][cc][e] * rr[su];
        *(f32x4*)&obuf[r_ + cc * 16] = o;
      }
    }
  }
  __syncthreads();
  const int row = t >> 3;
  const int cb = (t & 7) * 16;
  float* op = out + ((size_t)b * NN + qb * 64 + row) * DK + cb;
#pragma unroll
  for (int g = 0; g < 4; ++g)
    *(f32x4*)(op + g * 4) = *(const f32x4*)&obuf[row * 132 + cb + g * 4];
}

extern "C" void kernel_launch(void* const* d_in, const int* in_sizes, int n_in,
                              void* d_out, int out_size, void* d_ws, size_t ws_size,
                              hipStream_t stream) {
  const float* qt = (const float*)d_in[0];
  const float* kt = (const float*)d_in[1];
  const float* vt = (const float*)d_in[2];
  const float* kern = (const float*)d_in[3];
  float* out = (float*)d_out;

  char* ws = (char*)d_ws;
  float* qpart = (float*)(ws + 4096);         // 64*128 floats (32 KB)
  _Float16* khp = (_Float16*)(ws + 65536);    // 2M halfs (4 MB)
  _Float16* vTp = khp + (size_t)BS * NN * DK; // 2M halfs (4 MB)

  prep_k<<<dim3(1088), dim3(256), 0, stream>>>(kt, khp, vt, vTp, qt, qpart);
  attn_k<<<dim3(256), dim3(512), 0, stream>>>(qt, khp, vTp, kern, qpart, out);
}